// Round 2
// baseline (245.958 us; speedup 1.0000x reference)
//
#include <hip/hip_runtime.h>
#include <math.h>

// Problem constants (fixed by the reference file)
#define NN 100000
#define EE 1600000
#define DIM 128

// Partition parameters
#define BK 512                 // nodes per coarse bucket (dst >> 9)
#define NBK2 196               // ceil(NN / 512)
#define NCH 256                // edge-chunk blocks
#define EPB 6250               // EE / NCH
#define SCN (NBK2 * NCH)       // 50176 = 49 * 1024 exactly
#define NSB 49                 // scan blocks

typedef _Float16 half8 __attribute__((ext_vector_type(8)));
typedef _Float16 half2v __attribute__((ext_vector_type(2)));
typedef float f32x4 __attribute__((ext_vector_type(4)));

// ---------------------------------------------------------------------------
// Kernel 0: Bt[n*128+k] = W[n*128+k] * mask[k], cast fp16.
// ---------------------------------------------------------------------------
__global__ __launch_bounds__(256) void k_wt(const float* __restrict__ W,
                                            const float* __restrict__ mask,
                                            _Float16* __restrict__ Bt) {
    int o = blockIdx.x * 256 + threadIdx.x;
    if (o < DIM * DIM) Bt[o] = (_Float16)(W[o] * mask[o & 127]);
}

// ---------------------------------------------------------------------------
// Kernel 1: h = feat @ Bt^T via MFMA f32_16x16x32_f16, fp32 accumulate.
// Epilogue: sv[row] = exp(leaky_relu(h @ attn)) — softmax numerator per node
// (max-subtraction dropped: s bounded ±~3, exp(s)/sum(exp(s)) == reference).
// ---------------------------------------------------------------------------
__global__ __launch_bounds__(256) void k_gemm(const float* __restrict__ feat,
                                              const _Float16* __restrict__ Bt,
                                              const float* __restrict__ attn,
                                              _Float16* __restrict__ hh,
                                              float* __restrict__ s) {
    const int lane = threadIdx.x & 63;
    const int wv   = threadIdx.x >> 6;
    const int l15  = lane & 15;
    const int quad = lane >> 4;
    const int row0 = blockIdx.x * 64 + wv * 16;

    f32x4 acc[8];
#pragma unroll
    for (int nt = 0; nt < 8; ++nt) acc[nt] = (f32x4){0.f, 0.f, 0.f, 0.f};

    const int arow = row0 + l15;
    const bool okA = arow < NN;
    const float* ap = feat + (size_t)(okA ? arow : 0) * DIM + quad * 8;

#pragma unroll
    for (int kc = 0; kc < 4; ++kc) {
        half8 a;
        float4 f0 = ((const float4*)(ap + kc * 32))[0];
        float4 f1 = ((const float4*)(ap + kc * 32))[1];
        if (!okA) { f0 = make_float4(0, 0, 0, 0); f1 = make_float4(0, 0, 0, 0); }
        a[0] = (_Float16)f0.x; a[1] = (_Float16)f0.y;
        a[2] = (_Float16)f0.z; a[3] = (_Float16)f0.w;
        a[4] = (_Float16)f1.x; a[5] = (_Float16)f1.y;
        a[6] = (_Float16)f1.z; a[7] = (_Float16)f1.w;
#pragma unroll
        for (int nt = 0; nt < 8; ++nt) {
            half8 b = *(const half8*)(Bt + (size_t)(nt * 16 + l15) * DIM + kc * 32 + quad * 8);
            acc[nt] = __builtin_amdgcn_mfma_f32_16x16x32_f16(a, b, acc[nt], 0, 0, 0);
        }
    }

    float avv[8];
#pragma unroll
    for (int nt = 0; nt < 8; ++nt) avv[nt] = attn[nt * 16 + l15];

#pragma unroll
    for (int r = 0; r < 4; ++r) {
        int row = row0 + quad * 4 + r;
        float p = 0.f;
#pragma unroll
        for (int nt = 0; nt < 8; ++nt) p += acc[nt][r] * avv[nt];
        p += __shfl_xor(p, 1, 64);
        p += __shfl_xor(p, 2, 64);
        p += __shfl_xor(p, 4, 64);
        p += __shfl_xor(p, 8, 64);
        if (l15 == 0 && row < NN) {
            float lr = (p > 0.f) ? p : 0.01f * p;
            s[row] = __expf(lr);      // softmax numerator, per node
        }
    }

#pragma unroll
    for (int nt = 0; nt < 8; ++nt) {
#pragma unroll
        for (int r = 0; r < 4; ++r) {
            int row = row0 + quad * 4 + r;
            if (row < NN)
                hh[(size_t)row * DIM + nt * 16 + l15] = (_Float16)acc[nt][r];
        }
    }
}

// ---------------------------------------------------------------------------
// Kernel 2: per-block LDS histogram over coarse buckets. 1024 threads.
// ---------------------------------------------------------------------------
__global__ __launch_bounds__(1024) void k_bhist(const int* __restrict__ dst,
                                                int* __restrict__ gHist) {
    __shared__ int hist[NBK2];
    const int t = threadIdx.x, b = blockIdx.x;
    for (int i = t; i < NBK2; i += 1024) hist[i] = 0;
    __syncthreads();
    const int e0 = b * EPB;
    int e1 = e0 + EPB; if (e1 > EE) e1 = EE;
    for (int e = e0 + t; e < e1; e += 1024)
        atomicAdd(&hist[dst[e] >> 9], 1);
    __syncthreads();
    for (int i = t; i < NBK2; i += 1024)
        gHist[i * NCH + b] = hist[i];
}

// ---------------------------------------------------------------------------
// Kernels 3-4: exclusive scan of gHist (SCN = 49*1024 elements).
// boff (per-1024-chunk base) is applied by consumers: final offset of gHist
// element i is gHist[i] + boff[i>>10].
// ---------------------------------------------------------------------------
__global__ __launch_bounds__(256) void k_scan_a(const int* __restrict__ deg,
                                                int* __restrict__ excl,
                                                int* __restrict__ bsum) {
    __shared__ int wsum[4];
    __shared__ int woff[4];
    const int t = threadIdx.x, b = blockIdx.x;
    const int base = b * 1024 + t * 4;
    int v0 = deg[base + 0];
    int v1 = deg[base + 1];
    int v2 = deg[base + 2];
    int v3 = deg[base + 3];
    int tsum = v0 + v1 + v2 + v3;

    const int lane = t & 63, w = t >> 6;
    int incl = tsum;
#pragma unroll
    for (int d = 1; d < 64; d <<= 1) {
        int n = __shfl_up(incl, d, 64);
        if (lane >= d) incl += n;
    }
    if (lane == 63) wsum[w] = incl;
    __syncthreads();
    if (t == 0) {
        int run = 0;
#pragma unroll
        for (int i = 0; i < 4; ++i) { woff[i] = run; run += wsum[i]; }
        bsum[b] = run;
    }
    __syncthreads();
    int texcl = incl - tsum + woff[w];
    excl[base + 0] = texcl;
    excl[base + 1] = texcl + v0;
    excl[base + 2] = texcl + v0 + v1;
    excl[base + 3] = texcl + v0 + v1 + v2;
}

__global__ __launch_bounds__(64) void k_scan_b(const int* __restrict__ bsum,
                                               int* __restrict__ boff) {
    const int lane = threadIdx.x & 63;
    int v = (lane < NSB) ? bsum[lane] : 0;
    int incl = v;
#pragma unroll
    for (int d = 1; d < 64; d <<= 1) {
        int n = __shfl_up(incl, d, 64);
        if (lane >= d) incl += n;
    }
    if (lane < NSB) boff[lane] = incl - v;
}

// ---------------------------------------------------------------------------
// Kernel 5: partition scatter. Private contiguous region per (bucket,block)
// -> full-line writebacks, LDS-only atomics. boff folded in at cursor init.
// Payload: (src | dstLocal<<20, exp(s[src]) bits). 1024 threads.
// ---------------------------------------------------------------------------
__global__ __launch_bounds__(1024) void k_bscatter(const int* __restrict__ src,
                                                   const int* __restrict__ dst,
                                                   const float* __restrict__ s,
                                                   const int* __restrict__ gOff,
                                                   const int* __restrict__ boff,
                                                   int2* __restrict__ binned) {
    __shared__ int cur[NBK2];
    const int t = threadIdx.x, b = blockIdx.x;
    for (int i = t; i < NBK2; i += 1024) {
        int idx = i * NCH + b;
        cur[i] = gOff[idx] + boff[idx >> 10];
    }
    __syncthreads();
    const int e0 = b * EPB;
    int e1 = e0 + EPB; if (e1 > EE) e1 = EE;
    for (int e = e0 + t; e < e1; e += 1024) {
        int d  = dst[e];
        int si = src[e];
        float x = s[si];
        int bk   = d >> 9;
        int dloc = d & (BK - 1);
        int pos = atomicAdd(&cur[bk], 1);
        binned[pos] = make_int2(si | (dloc << 20), __float_as_int(x));
    }
}

// ---------------------------------------------------------------------------
// Kernel 6: per-bucket exact CSR placement + node CSR pointers. 1024 threads
// (16 waves/block — was 4; this kernel was the occupancy hole at 196 blocks).
// ---------------------------------------------------------------------------
__global__ __launch_bounds__(1024) void k_group(const int* __restrict__ gOff,
                                                const int* __restrict__ boff,
                                                const int2* __restrict__ binned,
                                                int2* __restrict__ pack,
                                                int* __restrict__ offs) {
    __shared__ int ldeg[BK];
    __shared__ int wpart[8];
    const int bk = blockIdx.x;
    const int t  = threadIdx.x;
    const int i0 = bk * NCH;
    const int base = gOff[i0] + boff[i0 >> 10];
    int endp;
    if (bk == NBK2 - 1) endp = EE;
    else {
        int i1 = (bk + 1) * NCH;
        endp = gOff[i1] + boff[i1 >> 10];
    }

    if (t < BK) ldeg[t] = 0;
    __syncthreads();
    for (int j = base + t; j < endp; j += 1024)
        atomicAdd(&ldeg[(binned[j].x >> 20) & (BK - 1)], 1);
    __syncthreads();

    // scan of 512 bins: first 512 threads (8 waves) + cross-wave combine
    int v = 0, incl = 0;
    const int lane = t & 63;
    if (t < BK) {
        v = ldeg[t];
        incl = v;
#pragma unroll
        for (int d = 1; d < 64; d <<= 1) {
            int n = __shfl_up(incl, d, 64);
            if (lane >= d) incl += n;
        }
        if (lane == 63) wpart[t >> 6] = incl;
    }
    __syncthreads();
    if (t == 0) {
        int run = 0;
#pragma unroll
        for (int i = 0; i < 8; ++i) { int tmp = wpart[i]; wpart[i] = run; run += tmp; }
    }
    __syncthreads();
    if (t < BK) {
        int excl = incl - v + wpart[t >> 6];
        int c = base + excl;
        int n = bk * BK + t;
        if (n < NN) offs[n] = c;
        ldeg[t] = c;                       // becomes the placement cursor
    }
    if (bk == NBK2 - 1 && t == 0) offs[NN] = EE;
    __syncthreads();

    for (int j = base + t; j < endp; j += 1024) {
        int2 e = binned[j];
        int dloc = (e.x >> 20) & (BK - 1);
        int si   = e.x & 0xFFFFF;
        int pos = atomicAdd(&ldeg[dloc], 1);
        pack[pos] = make_int2(si, e.y);
    }
}

// ---------------------------------------------------------------------------
// Kernel 7 (v2): one wave per dst node, QUARTER-WAVE row gather.
// 16 lanes x half8 (16 B/lane) cover one 256-B hh row -> one dwordx4 gather
// instruction fetches 4 edges' rows (4x fewer VMEM issues + addr VALU than
// the per-edge 64-lane half2 gather). Each quarter-wave accumulates the full
// 128 channels (lane li holds channels li*8..li*8+7); shfl_xor(16/32)
// combines the 4 groups. Tail: wave-uniform branches, clamped index, zero
// weight.
// ---------------------------------------------------------------------------
__global__ __launch_bounds__(256) void k_agg(const _Float16* __restrict__ hh,
                                             const int* __restrict__ offs,
                                             const int2* __restrict__ pack,
                                             float* __restrict__ out) {
    const int lane = threadIdx.x & 63;
    const int g    = lane >> 4;        // quarter-wave group 0..3
    const int li   = lane & 15;        // lane within group
    const int wid  = __builtin_amdgcn_readfirstlane(blockIdx.x * 4 + (threadIdx.x >> 6));
    if (wid >= NN) return;
    const int beg = __builtin_amdgcn_readfirstlane(offs[wid]);
    const int end = __builtin_amdgcn_readfirstlane(offs[wid + 1]);

    const half8* h8 = (const half8*)hh;   // row = 16 half8 chunks
    float acc[8];
#pragma unroll
    for (int k = 0; k < 8; ++k) acc[k] = 0.f;
    float l = 0.f;

    int p = beg;
    // main loop: 8 edges per iteration (2 per group), 2 gathers in flight
    for (; p + 8 <= end; p += 8) {
        int2 e0 = pack[p + g];
        int2 e1 = pack[p + 4 + g];
        half8 v0 = h8[((unsigned)e0.x << 4) + li];
        half8 v1 = h8[((unsigned)e1.x << 4) + li];
        float w0 = __int_as_float(e0.y);
        float w1 = __int_as_float(e1.y);
#pragma unroll
        for (int k = 0; k < 8; ++k) acc[k] = fmaf((float)v0[k], w0, acc[k]);
#pragma unroll
        for (int k = 0; k < 8; ++k) acc[k] = fmaf((float)v1[k], w1, acc[k]);
        l += w0 + w1;
    }

    const int rem = end - p;            // 0..7, wave-uniform
    if (rem > 0) {
        const int last = end - 1;
        int q0 = p + g;
        int2 e0 = pack[q0 <= last ? q0 : last];
        half8 v0 = h8[((unsigned)e0.x << 4) + li];
        float w0 = (g < rem) ? __int_as_float(e0.y) : 0.f;
#pragma unroll
        for (int k = 0; k < 8; ++k) acc[k] = fmaf((float)v0[k], w0, acc[k]);
        l += w0;
        if (rem > 4) {
            int q1 = p + 4 + g;
            int2 e1 = pack[q1 <= last ? q1 : last];
            half8 v1 = h8[((unsigned)e1.x << 4) + li];
            float w1 = (4 + g < rem) ? __int_as_float(e1.y) : 0.f;
#pragma unroll
            for (int k = 0; k < 8; ++k) acc[k] = fmaf((float)v1[k], w1, acc[k]);
            l += w1;
        }
    }

    // cross-group combine: 4 groups hold partials for the same channels
#pragma unroll
    for (int k = 0; k < 8; ++k) {
        acc[k] += __shfl_xor(acc[k], 16, 64);
        acc[k] += __shfl_xor(acc[k], 32, 64);
    }
    l += __shfl_xor(l, 16, 64);
    l += __shfl_xor(l, 32, 64);

    float inv = (l > 0.f) ? (1.0f / l) : 0.f;

    // store: group 0's 16 lanes write 32 B each -> contiguous 512 B per node
    if (g == 0) {
        float4 o0, o1;
        o0.x = fmaxf(acc[0] * inv, 0.f);
        o0.y = fmaxf(acc[1] * inv, 0.f);
        o0.z = fmaxf(acc[2] * inv, 0.f);
        o0.w = fmaxf(acc[3] * inv, 0.f);
        o1.x = fmaxf(acc[4] * inv, 0.f);
        o1.y = fmaxf(acc[5] * inv, 0.f);
        o1.z = fmaxf(acc[6] * inv, 0.f);
        o1.w = fmaxf(acc[7] * inv, 0.f);
        float4* op = (float4*)(out + (size_t)wid * DIM + li * 8);
        op[0] = o0;
        op[1] = o1;
    }
}

// ---------------------------------------------------------------------------
extern "C" void kernel_launch(void* const* d_in, const int* in_sizes, int n_in,
                              void* d_out, int out_size, void* d_ws, size_t ws_size,
                              hipStream_t stream) {
    const float* feat = (const float*)d_in[0];
    const float* mask = (const float*)d_in[1];
    const float* W    = (const float*)d_in[2];
    const float* attn = (const float*)d_in[3];
    const int*   src  = (const int*)d_in[4];
    const int*   dst  = (const int*)d_in[5];
    float* out = (float*)d_out;

    // Workspace carve-up (~52.5 MB total)
    char* ws = (char*)d_ws;
    size_t off = 0;
    auto alloc = [&](size_t bytes) -> void* {
        void* p = ws + off;
        off = (off + bytes + 511) & ~(size_t)511;
        return p;
    };
    _Float16* hh  = (_Float16*)alloc((size_t)NN * DIM * 2); // 25.6 MB
    float*  sv    = (float*)alloc((size_t)NN * 4);
    _Float16* Bt  = (_Float16*)alloc((size_t)DIM * DIM * 2);
    int*    gOff  = (int*)alloc((size_t)SCN * 4);           // 200 KB
    int*    offs  = (int*)alloc((size_t)(NN + 1) * 4);
    int*    bsum  = (int*)alloc((size_t)NSB * 4);
    int*    boff  = (int*)alloc((size_t)NSB * 4);
    int2*   binned= (int2*)alloc((size_t)EE * 8);           // 12.8 MB
    int2*   pack  = (int2*)alloc((size_t)EE * 8);           // 12.8 MB

    k_wt<<<(DIM * DIM + 255) / 256, 256, 0, stream>>>(W, mask, Bt);
    k_gemm<<<(NN + 63) / 64, 256, 0, stream>>>(feat, Bt, attn, hh, sv);
    k_bhist<<<NCH, 1024, 0, stream>>>(dst, gOff);
    k_scan_a<<<NSB, 256, 0, stream>>>(gOff, gOff, bsum);
    k_scan_b<<<1, 64, 0, stream>>>(bsum, boff);
    k_bscatter<<<NCH, 1024, 0, stream>>>(src, dst, sv, gOff, boff, binned);
    k_group<<<NBK2, 1024, 0, stream>>>(gOff, boff, binned, pack, offs);
    k_agg<<<(NN + 3) / 4, 256, 0, stream>>>(hh, offs, pack, out);
}

// Round 4
// 245.119 us; speedup vs baseline: 1.0034x; 1.0034x over previous
//
#include <hip/hip_runtime.h>
#include <math.h>

// Problem constants (fixed by the reference file)
#define NN 100000
#define EE 1600000
#define DIM 128

// Partition parameters
#define BK 512                 // nodes per coarse bucket (dst >> 9)
#define NBK2 196               // ceil(NN / 512)
#define NCH 256                // edge-chunk blocks
#define EPB 6250               // EE / NCH
#define SCN (NBK2 * NCH)       // 50176 = 49 * 1024 exactly
#define NSB 49                 // scan blocks

typedef _Float16 half8 __attribute__((ext_vector_type(8)));
typedef _Float16 half2v __attribute__((ext_vector_type(2)));
typedef float f32x4 __attribute__((ext_vector_type(4)));

// ---------------------------------------------------------------------------
// Kernel 0: Bt[n*128+k] = W[n*128+k] * mask[k], cast fp16.
// ---------------------------------------------------------------------------
__global__ __launch_bounds__(256) void k_wt(const float* __restrict__ W,
                                            const float* __restrict__ mask,
                                            _Float16* __restrict__ Bt) {
    int o = blockIdx.x * 256 + threadIdx.x;
    if (o < DIM * DIM) Bt[o] = (_Float16)(W[o] * mask[o & 127]);
}

// ---------------------------------------------------------------------------
// Kernel 1: h = feat @ Bt^T via MFMA f32_16x16x32_f16, fp32 accumulate.
// Epilogue: sv[row] = exp(leaky_relu(h @ attn)) — softmax numerator per node
// (max-subtraction dropped: s bounded ±~3, exp(s)/sum(exp(s)) == reference).
// ---------------------------------------------------------------------------
__global__ __launch_bounds__(256) void k_gemm(const float* __restrict__ feat,
                                              const _Float16* __restrict__ Bt,
                                              const float* __restrict__ attn,
                                              _Float16* __restrict__ hh,
                                              float* __restrict__ s) {
    const int lane = threadIdx.x & 63;
    const int wv   = threadIdx.x >> 6;
    const int l15  = lane & 15;
    const int quad = lane >> 4;
    const int row0 = blockIdx.x * 64 + wv * 16;

    f32x4 acc[8];
#pragma unroll
    for (int nt = 0; nt < 8; ++nt) acc[nt] = (f32x4){0.f, 0.f, 0.f, 0.f};

    const int arow = row0 + l15;
    const bool okA = arow < NN;
    const float* ap = feat + (size_t)(okA ? arow : 0) * DIM + quad * 8;

#pragma unroll
    for (int kc = 0; kc < 4; ++kc) {
        half8 a;
        float4 f0 = ((const float4*)(ap + kc * 32))[0];
        float4 f1 = ((const float4*)(ap + kc * 32))[1];
        if (!okA) { f0 = make_float4(0, 0, 0, 0); f1 = make_float4(0, 0, 0, 0); }
        a[0] = (_Float16)f0.x; a[1] = (_Float16)f0.y;
        a[2] = (_Float16)f0.z; a[3] = (_Float16)f0.w;
        a[4] = (_Float16)f1.x; a[5] = (_Float16)f1.y;
        a[6] = (_Float16)f1.z; a[7] = (_Float16)f1.w;
#pragma unroll
        for (int nt = 0; nt < 8; ++nt) {
            half8 b = *(const half8*)(Bt + (size_t)(nt * 16 + l15) * DIM + kc * 32 + quad * 8);
            acc[nt] = __builtin_amdgcn_mfma_f32_16x16x32_f16(a, b, acc[nt], 0, 0, 0);
        }
    }

    float avv[8];
#pragma unroll
    for (int nt = 0; nt < 8; ++nt) avv[nt] = attn[nt * 16 + l15];

#pragma unroll
    for (int r = 0; r < 4; ++r) {
        int row = row0 + quad * 4 + r;
        float p = 0.f;
#pragma unroll
        for (int nt = 0; nt < 8; ++nt) p += acc[nt][r] * avv[nt];
        p += __shfl_xor(p, 1, 64);
        p += __shfl_xor(p, 2, 64);
        p += __shfl_xor(p, 4, 64);
        p += __shfl_xor(p, 8, 64);
        if (l15 == 0 && row < NN) {
            float lr = (p > 0.f) ? p : 0.01f * p;
            s[row] = __expf(lr);      // softmax numerator, per node
        }
    }

#pragma unroll
    for (int nt = 0; nt < 8; ++nt) {
#pragma unroll
        for (int r = 0; r < 4; ++r) {
            int row = row0 + quad * 4 + r;
            if (row < NN)
                hh[(size_t)row * DIM + nt * 16 + l15] = (_Float16)acc[nt][r];
        }
    }
}

// ---------------------------------------------------------------------------
// Kernel 2: per-block LDS histogram over coarse buckets. 1024 threads.
// ---------------------------------------------------------------------------
__global__ __launch_bounds__(1024) void k_bhist(const int* __restrict__ dst,
                                                int* __restrict__ gHist) {
    __shared__ int hist[NBK2];
    const int t = threadIdx.x, b = blockIdx.x;
    for (int i = t; i < NBK2; i += 1024) hist[i] = 0;
    __syncthreads();
    const int e0 = b * EPB;
    int e1 = e0 + EPB; if (e1 > EE) e1 = EE;
    for (int e = e0 + t; e < e1; e += 1024)
        atomicAdd(&hist[dst[e] >> 9], 1);
    __syncthreads();
    for (int i = t; i < NBK2; i += 1024)
        gHist[i * NCH + b] = hist[i];
}

// ---------------------------------------------------------------------------
// Kernels 3-4: exclusive scan of gHist (SCN = 49*1024 elements).
// boff (per-1024-chunk base) is applied by consumers: final offset of gHist
// element i is gHist[i] + boff[i>>10].
// ---------------------------------------------------------------------------
__global__ __launch_bounds__(256) void k_scan_a(const int* __restrict__ deg,
                                                int* __restrict__ excl,
                                                int* __restrict__ bsum) {
    __shared__ int wsum[4];
    __shared__ int woff[4];
    const int t = threadIdx.x, b = blockIdx.x;
    const int base = b * 1024 + t * 4;
    int v0 = deg[base + 0];
    int v1 = deg[base + 1];
    int v2 = deg[base + 2];
    int v3 = deg[base + 3];
    int tsum = v0 + v1 + v2 + v3;

    const int lane = t & 63, w = t >> 6;
    int incl = tsum;
#pragma unroll
    for (int d = 1; d < 64; d <<= 1) {
        int n = __shfl_up(incl, d, 64);
        if (lane >= d) incl += n;
    }
    if (lane == 63) wsum[w] = incl;
    __syncthreads();
    if (t == 0) {
        int run = 0;
#pragma unroll
        for (int i = 0; i < 4; ++i) { woff[i] = run; run += wsum[i]; }
        bsum[b] = run;
    }
    __syncthreads();
    int texcl = incl - tsum + woff[w];
    excl[base + 0] = texcl;
    excl[base + 1] = texcl + v0;
    excl[base + 2] = texcl + v0 + v1;
    excl[base + 3] = texcl + v0 + v1 + v2;
}

__global__ __launch_bounds__(64) void k_scan_b(const int* __restrict__ bsum,
                                               int* __restrict__ boff) {
    const int lane = threadIdx.x & 63;
    int v = (lane < NSB) ? bsum[lane] : 0;
    int incl = v;
#pragma unroll
    for (int d = 1; d < 64; d <<= 1) {
        int n = __shfl_up(incl, d, 64);
        if (lane >= d) incl += n;
    }
    if (lane < NSB) boff[lane] = incl - v;
}

// ---------------------------------------------------------------------------
// Kernel 5: partition scatter. Private contiguous region per (bucket,block)
// -> full-line writebacks, LDS-only atomics. boff folded in at cursor init.
// Payload: (src | dstLocal<<20, exp(s[src]) bits). 1024 threads.
// ---------------------------------------------------------------------------
__global__ __launch_bounds__(1024) void k_bscatter(const int* __restrict__ src,
                                                   const int* __restrict__ dst,
                                                   const float* __restrict__ s,
                                                   const int* __restrict__ gOff,
                                                   const int* __restrict__ boff,
                                                   int2* __restrict__ binned) {
    __shared__ int cur[NBK2];
    const int t = threadIdx.x, b = blockIdx.x;
    for (int i = t; i < NBK2; i += 1024) {
        int idx = i * NCH + b;
        cur[i] = gOff[idx] + boff[idx >> 10];
    }
    __syncthreads();
    const int e0 = b * EPB;
    int e1 = e0 + EPB; if (e1 > EE) e1 = EE;
    for (int e = e0 + t; e < e1; e += 1024) {
        int d  = dst[e];
        int si = src[e];
        float x = s[si];
        int bk   = d >> 9;
        int dloc = d & (BK - 1);
        int pos = atomicAdd(&cur[bk], 1);
        binned[pos] = make_int2(si | (dloc << 20), __float_as_int(x));
    }
}

// ---------------------------------------------------------------------------
// Kernel 6: per-bucket exact CSR placement + node CSR pointers. 1024 threads
// (16 waves/block — was 4; this kernel was the occupancy hole at 196 blocks).
// ---------------------------------------------------------------------------
__global__ __launch_bounds__(1024) void k_group(const int* __restrict__ gOff,
                                                const int* __restrict__ boff,
                                                const int2* __restrict__ binned,
                                                int2* __restrict__ pack,
                                                int* __restrict__ offs) {
    __shared__ int ldeg[BK];
    __shared__ int wpart[8];
    const int bk = blockIdx.x;
    const int t  = threadIdx.x;
    const int i0 = bk * NCH;
    const int base = gOff[i0] + boff[i0 >> 10];
    int endp;
    if (bk == NBK2 - 1) endp = EE;
    else {
        int i1 = (bk + 1) * NCH;
        endp = gOff[i1] + boff[i1 >> 10];
    }

    if (t < BK) ldeg[t] = 0;
    __syncthreads();
    for (int j = base + t; j < endp; j += 1024)
        atomicAdd(&ldeg[(binned[j].x >> 20) & (BK - 1)], 1);
    __syncthreads();

    // scan of 512 bins: first 512 threads (8 waves) + cross-wave combine
    int v = 0, incl = 0;
    const int lane = t & 63;
    if (t < BK) {
        v = ldeg[t];
        incl = v;
#pragma unroll
        for (int d = 1; d < 64; d <<= 1) {
            int n = __shfl_up(incl, d, 64);
            if (lane >= d) incl += n;
        }
        if (lane == 63) wpart[t >> 6] = incl;
    }
    __syncthreads();
    if (t == 0) {
        int run = 0;
#pragma unroll
        for (int i = 0; i < 8; ++i) { int tmp = wpart[i]; wpart[i] = run; run += tmp; }
    }
    __syncthreads();
    if (t < BK) {
        int excl = incl - v + wpart[t >> 6];
        int c = base + excl;
        int n = bk * BK + t;
        if (n < NN) offs[n] = c;
        ldeg[t] = c;                       // becomes the placement cursor
    }
    if (bk == NBK2 - 1 && t == 0) offs[NN] = EE;
    __syncthreads();

    for (int j = base + t; j < endp; j += 1024) {
        int2 e = binned[j];
        int dloc = (e.x >> 20) & (BK - 1);
        int si   = e.x & 0xFFFFF;
        int pos = atomicAdd(&ldeg[dloc], 1);
        pack[pos] = make_int2(si, e.y);
    }
}

// ---------------------------------------------------------------------------
// Kernel 7 (v3): one wave per dst node, LATENCY-ORIENTED.
// Step 1: ONE vector load fetches up to 64 edges' pack entries (lane = edge
//         slot) — the pack round trip happens once per node, not per 8 edges.
// Step 2: quarter-wave row gather (16 lanes x half8 = one 256-B row); the
//         (src, w) of each edge is broadcast to the gather groups via
//         __shfl (ds_bpermute — off the HBM critical path). Gather steps are
//         explicitly unrolled x4 so 4 row-gathers are in flight with NO
//         serial dependence between them.
// Out-of-range edge slots: index clamped to a valid row, weight forced to 0.
// ---------------------------------------------------------------------------
__global__ __launch_bounds__(256) void k_agg(const _Float16* __restrict__ hh,
                                             const int* __restrict__ offs,
                                             const int2* __restrict__ pack,
                                             float* __restrict__ out) {
    const int lane = threadIdx.x & 63;
    const int g    = lane >> 4;        // quarter-wave group 0..3
    const int li   = lane & 15;        // lane within group
    const int wid  = __builtin_amdgcn_readfirstlane(blockIdx.x * 4 + (threadIdx.x >> 6));
    if (wid >= NN) return;
    const int beg = __builtin_amdgcn_readfirstlane(offs[wid]);
    const int end = __builtin_amdgcn_readfirstlane(offs[wid + 1]);
    const int deg = end - beg;

    const half8* h8 = (const half8*)hh;   // row = 16 half8 chunks
    float acc[8];
#pragma unroll
    for (int k = 0; k < 8; ++k) acc[k] = 0.f;
    float lsum = 0.f;                  // per-lane (lane == edge slot) partial

    for (int base = 0; base < deg; base += 64) {
        const int nrem = deg - base;              // > 0, wave-uniform
        const int idx  = base + lane;
        const int cl   = (idx < deg) ? idx : (deg - 1);
        const int2 e   = pack[beg + cl];          // 64 edges in ONE load
        const float w  = (idx < deg) ? __int_as_float(e.y) : 0.f;
        lsum += w;
        const int cmax = (nrem < 64) ? nrem : 64; // wave-uniform bound
        // chunks of 16 edges = 4 independent gather steps, unrolled
        for (int c0 = 0; c0 < cmax; c0 += 16) {
#pragma unroll
            for (int s = 0; s < 4; ++s) {
                const int ei = c0 + s * 4 + g;    // edge slot 0..63
                const int   si = __shfl(e.x, ei, 64);
                const float wg = __shfl(w,   ei, 64);  // 0 for invalid slots
                half8 v = h8[((unsigned)si << 4) + li];
#pragma unroll
                for (int k = 0; k < 8; ++k)
                    acc[k] = fmaf((float)v[k], wg, acc[k]);
            }
        }
    }

    // cross-group combine: 4 groups hold partials for the same channels
#pragma unroll
    for (int k = 0; k < 8; ++k) {
        acc[k] += __shfl_xor(acc[k], 16, 64);
        acc[k] += __shfl_xor(acc[k], 32, 64);
    }
    // full-wave sum of weights (lsum is distributed over all 64 lanes)
    lsum += __shfl_xor(lsum, 1, 64);
    lsum += __shfl_xor(lsum, 2, 64);
    lsum += __shfl_xor(lsum, 4, 64);
    lsum += __shfl_xor(lsum, 8, 64);
    lsum += __shfl_xor(lsum, 16, 64);
    lsum += __shfl_xor(lsum, 32, 64);

    const float inv = (lsum > 0.f) ? (1.0f / lsum) : 0.f;

    // store: group 0's 16 lanes write 32 B each -> contiguous 512 B per node
    if (g == 0) {
        float4 o0, o1;
        o0.x = fmaxf(acc[0] * inv, 0.f);
        o0.y = fmaxf(acc[1] * inv, 0.f);
        o0.z = fmaxf(acc[2] * inv, 0.f);
        o0.w = fmaxf(acc[3] * inv, 0.f);
        o1.x = fmaxf(acc[4] * inv, 0.f);
        o1.y = fmaxf(acc[5] * inv, 0.f);
        o1.z = fmaxf(acc[6] * inv, 0.f);
        o1.w = fmaxf(acc[7] * inv, 0.f);
        float4* op = (float4*)(out + (size_t)wid * DIM + li * 8);
        op[0] = o0;
        op[1] = o1;
    }
}

// ---------------------------------------------------------------------------
extern "C" void kernel_launch(void* const* d_in, const int* in_sizes, int n_in,
                              void* d_out, int out_size, void* d_ws, size_t ws_size,
                              hipStream_t stream) {
    const float* feat = (const float*)d_in[0];
    const float* mask = (const float*)d_in[1];
    const float* W    = (const float*)d_in[2];
    const float* attn = (const float*)d_in[3];
    const int*   src  = (const int*)d_in[4];
    const int*   dst  = (const int*)d_in[5];
    float* out = (float*)d_out;

    // Workspace carve-up (~52.5 MB total)
    char* ws = (char*)d_ws;
    size_t off = 0;
    auto alloc = [&](size_t bytes) -> void* {
        void* p = ws + off;
        off = (off + bytes + 511) & ~(size_t)511;
        return p;
    };
    _Float16* hh  = (_Float16*)alloc((size_t)NN * DIM * 2); // 25.6 MB
    float*  sv    = (float*)alloc((size_t)NN * 4);
    _Float16* Bt  = (_Float16*)alloc((size_t)DIM * DIM * 2);
    int*    gOff  = (int*)alloc((size_t)SCN * 4);           // 200 KB
    int*    offs  = (int*)alloc((size_t)(NN + 1) * 4);
    int*    bsum  = (int*)alloc((size_t)NSB * 4);
    int*    boff  = (int*)alloc((size_t)NSB * 4);
    int2*   binned= (int2*)alloc((size_t)EE * 8);           // 12.8 MB
    int2*   pack  = (int2*)alloc((size_t)EE * 8);           // 12.8 MB

    k_wt<<<(DIM * DIM + 255) / 256, 256, 0, stream>>>(W, mask, Bt);
    k_gemm<<<(NN + 63) / 64, 256, 0, stream>>>(feat, Bt, attn, hh, sv);
    k_bhist<<<NCH, 1024, 0, stream>>>(dst, gOff);
    k_scan_a<<<NSB, 256, 0, stream>>>(gOff, gOff, bsum);
    k_scan_b<<<1, 64, 0, stream>>>(bsum, boff);
    k_bscatter<<<NCH, 1024, 0, stream>>>(src, dst, sv, gOff, boff, binned);
    k_group<<<NBK2, 1024, 0, stream>>>(gOff, boff, binned, pack, offs);
    k_agg<<<(NN + 3) / 4, 256, 0, stream>>>(hh, offs, pack, out);
}